// Round 5
// baseline (16570.860 us; speedup 1.0000x reference)
//
#include <hip/hip_runtime.h>
#include <cstdint>

#define NPTS 32768
#define DIM  256
#define NK   128
#define NITER 100
#define NBLK 256
#define NTHR 512

typedef unsigned short ushort_t;
typedef __attribute__((ext_vector_type(8))) short s8v;   // 8 bf16 in 4 VGPRs
typedef __attribute__((ext_vector_type(4))) float f4v;   // MFMA accumulator

__device__ __forceinline__ unsigned short f2bf(float f) {
  unsigned u = __float_as_uint(f);
  u += 0x7fffu + ((u >> 16) & 1u);      // RTNE
  return (unsigned short)(u >> 16);
}
__device__ __forceinline__ float bf2f(unsigned short b) {
  return __uint_as_float(((unsigned)b) << 16);
}

// ---- device-scope grid barrier (sense-reversal), state in d_ws, zeroed per launch ----
__device__ __forceinline__ void gbar(unsigned* bar) {
  __syncthreads();
  if (threadIdx.x == 0) {
    __threadfence();
    unsigned g = __hip_atomic_load(&bar[1], __ATOMIC_RELAXED, __HIP_MEMORY_SCOPE_AGENT);
    unsigned a = __hip_atomic_fetch_add(&bar[0], 1u, __ATOMIC_ACQ_REL, __HIP_MEMORY_SCOPE_AGENT);
    if (a == (unsigned)NBLK - 1u) {
      __hip_atomic_store(&bar[0], 0u, __ATOMIC_RELAXED, __HIP_MEMORY_SCOPE_AGENT);
      __hip_atomic_store(&bar[1], g + 1u, __ATOMIC_RELEASE, __HIP_MEMORY_SCOPE_AGENT);
    } else {
      while (__hip_atomic_load(&bar[1], __ATOMIC_RELAXED, __HIP_MEMORY_SCOPE_AGENT) == g) {
        __builtin_amdgcn_s_sleep(2);
      }
    }
    __threadfence();
  }
  __syncthreads();
}

// LDS overlay: A = assign GEMM, B = update accumulator, C = small reduces
union SMu {
  struct {
    s8v bufs[4][2048];        // XH, XL, CH, CL half-D tiles, 32 KB each = 128 KB
    float cns[NK];
    float redd[NK * 4];
    int   redk[NK * 4];
    float gmaxs[NK];
    float labvs[NK];
    int   labis[NK];
  } a;
  struct {
    float ls[NK * DIM];       // 128 KB fp32 partial sums (aliases bufs exactly)
  } b;
  struct {
    float red[NTHR];
  } c;
};

// 8-wave (2 row x 4 col) 3-pass hi/lo bf16 MFMA GEMM: acc[i][j][r] = x_p . c_k
__device__ __forceinline__ void gemm_core(
    SMu& sm, int b, int t,
    const ushort_t* __restrict__ xh, const ushort_t* __restrict__ xl,
    const ushort_t* __restrict__ chi, const ushort_t* __restrict__ clo,
    const float* __restrict__ cn, f4v (&acc)[4][2]) {
  const int lane = t & 63;
  const int w    = t >> 6;
  const int wr   = w >> 2, wc = w & 3;    // 2x4 wave grid: 64 pts x 32 clusters each
  const int g    = lane >> 4, lr = lane & 15;
  const int pbase = b * 128;

  if (t < NK) sm.a.cns[t] = cn[t];

  const f4v zero = {0.f, 0.f, 0.f, 0.f};
#pragma unroll
  for (int i = 0; i < 4; ++i)
#pragma unroll
    for (int j = 0; j < 2; ++j) acc[i][j] = zero;

  const int swz = (lr & 7) << 4;
  int a_off[4], b_off[2];
#pragma unroll
  for (int i = 0; i < 4; ++i) a_off[i] = (wr * 64 + i * 16 + lr) * 256 + g * 16;
#pragma unroll
  for (int j = 0; j < 2; ++j) b_off[j] = (wc * 32 + j * 16 + lr) * 256 + g * 16;

  const ushort_t* srcs[4];
  srcs[0] = xh + pbase * DIM;
  srcs[1] = xl + pbase * DIM;
  srcs[2] = chi;
  srcs[3] = clo;

  for (int h = 0; h < 2; ++h) {           // two D-halves of 128
    __syncthreads();
#pragma unroll
    for (int bb = 0; bb < 4; ++bb) {
      const char* sp = (const char*)srcs[bb];
      char* dp = (char*)sm.a.bufs[bb];
#pragma unroll
      for (int i = 0; i < 4; ++i) {
        int gg = i * NTHR + t;            // granule within 32KB buffer
        int row = gg >> 4, whb = (gg & 15) * 16;
        s8v v = *(const s8v*)(sp + row * 512 + h * 256 + whb);
        *(s8v*)(dp + ((gg * 16) ^ ((row & 7) << 4))) = v;
      }
    }
    __syncthreads();
#pragma unroll
    for (int kk = 0; kk < 4; ++kk) {      // K=128 per half, 4 steps of 32
      s8v ah[4], al[4], bh[2], bl[2];
#pragma unroll
      for (int i = 0; i < 4; ++i) {
        int o = (a_off[i] + kk * 64) ^ swz;
        ah[i] = *(const s8v*)((const char*)sm.a.bufs[0] + o);
        al[i] = *(const s8v*)((const char*)sm.a.bufs[1] + o);
      }
#pragma unroll
      for (int j = 0; j < 2; ++j) {
        int o = (b_off[j] + kk * 64) ^ swz;
        bh[j] = *(const s8v*)((const char*)sm.a.bufs[2] + o);
        bl[j] = *(const s8v*)((const char*)sm.a.bufs[3] + o);
      }
#pragma unroll
      for (int i = 0; i < 4; ++i)
#pragma unroll
        for (int j = 0; j < 2; ++j) {
          acc[i][j] = __builtin_amdgcn_mfma_f32_16x16x32_bf16(ah[i], bh[j], acc[i][j], 0, 0, 0);
          acc[i][j] = __builtin_amdgcn_mfma_f32_16x16x32_bf16(ah[i], bl[j], acc[i][j], 0, 0, 0);
          acc[i][j] = __builtin_amdgcn_mfma_f32_16x16x32_bf16(al[i], bh[j], acc[i][j], 0, 0, 0);
        }
    }
  }
}

__global__ __launch_bounds__(NTHR, 1) void kmeans_fused(
    const float* __restrict__ x, const int* __restrict__ init_idx,
    ushort_t* __restrict__ xh, ushort_t* __restrict__ xl,
    ushort_t* __restrict__ chi, ushort_t* __restrict__ clo,
    float* __restrict__ cn, int* __restrict__ ids,
    float* __restrict__ psum, float* __restrict__ pcnt,
    float* __restrict__ outp, unsigned* __restrict__ bar,
    float* __restrict__ out) {
  __shared__ SMu sm;
  __shared__ int ids_loc[NK];
  __shared__ float4 redc4[8 * 64];        // phase-C cross-wave partials (8 KB)

  const int b = blockIdx.x;
  const int t = threadIdx.x;
  const int lane = t & 63;
  const int w  = t >> 6;
  const int wr = w >> 2, wc = w & 3;
  const int g  = lane >> 4, lr = lane & 15;
  const int pbase = b * 128;

  // ---------------- prep: x -> bf16 hi/lo images (once) ----------------
  for (int i = 0; i < 8; ++i) {
    int gg = b * 4096 + i * NTHR + t;     // 16B out-granule = 8 elems
    const float4* src = (const float4*)x + gg * 2;
    float4 fa = src[0], fb = src[1];
    float vv[8] = {fa.x, fa.y, fa.z, fa.w, fb.x, fb.y, fb.z, fb.w};
    s8v vh, vl;
#pragma unroll
    for (int j = 0; j < 8; ++j) {
      unsigned short hh = f2bf(vv[j]);
      vh[j] = (short)hh;
      vl[j] = (short)f2bf(vv[j] - bf2f(hh));
    }
    ((s8v*)xh)[gg] = vh;
    ((s8v*)xl)[gg] = vl;
  }

  // ---------------- init: c0 = x[init_idx] -> hi/lo + cn ----------------
  if (b < NK) {
    float eff = 0.f;
    if (t < DIM) {
      float v = x[init_idx[b] * DIM + t];
      unsigned short hh = f2bf(v);
      unsigned short ll = f2bf(v - bf2f(hh));
      chi[b * DIM + t] = hh;
      clo[b * DIM + t] = ll;
      eff = bf2f(hh) + bf2f(ll);
    }
    sm.c.red[t] = eff * eff;
    __syncthreads();
    for (int s = 256; s > 0; s >>= 1) { if (t < s) sm.c.red[t] += sm.c.red[t + s]; __syncthreads(); }
    if (t == 0) cn[b] = sm.c.red[0];
  }
  gbar(bar);

  // ---------------- main loop: 100 x (assign -> update-partial | reduce) ----------------
  for (int it = 0; it < NITER; ++it) {
    // ---- phase A: assign (ids stay block-local) ----
    {
      f4v acc[4][2];
      gemm_core(sm, b, t, xh, xl, chi, clo, cn, acc);
      // D layout: col(cluster) = lane&15, row(point in 16x16) = (lane>>4)*4 + reg
#pragma unroll
      for (int i = 0; i < 4; ++i) {
#pragma unroll
        for (int r = 0; r < 4; ++r) {
          int prow = wr * 64 + i * 16 + g * 4 + r;
          float bd = 1e30f; int bk = 0;
#pragma unroll
          for (int j = 0; j < 2; ++j) {
            int col = wc * 32 + j * 16 + lr;
            float s = sm.a.cns[col] - 2.f * acc[i][j][r];
            if (s < bd || (s == bd && col < bk)) { bd = s; bk = col; }
          }
#pragma unroll
          for (int msk = 1; msk < 16; msk <<= 1) {
            float od = __shfl_xor(bd, msk, 64);
            int   ok = __shfl_xor(bk, msk, 64);
            if (od < bd || (od == bd && ok < bk)) { bd = od; bk = ok; }
          }
          if (lr == 0) { sm.a.redd[prow * 4 + wc] = bd; sm.a.redk[prow * 4 + wc] = bk; }
        }
      }
      __syncthreads();
      if (t < NK) {
        float bd = sm.a.redd[t * 4]; int bk = sm.a.redk[t * 4];
#pragma unroll
        for (int q = 1; q < 4; ++q) {
          float dq = sm.a.redd[t * 4 + q]; int kq = sm.a.redk[t * 4 + q];
          if (dq < bd || (dq == bd && kq < bk)) { bd = dq; bk = kq; }
        }
        ids_loc[t] = bk;
        if (it == NITER - 1) ids[pbase + t] = bk;   // only needed for final loss labels
      }
    }

    // ---- phase B: block-local segment-sum into LDS (no barrier needed after A) ----
    {
      float4* ls4 = (float4*)sm.b.ls;
#pragma unroll
      for (int i = 0; i < 16; ++i) ls4[i * NTHR + t] = make_float4(0.f, 0.f, 0.f, 0.f);
      __syncthreads();
      const float* xb = x + (size_t)pbase * DIM;
      for (int s = 0; s < 16; ++s) {
        int p = s * 8 + w;                // each of 8 waves owns 16 points
        int id = ids_loc[p];
        const float* xr = xb + p * DIM;
#pragma unroll
        for (int cch = 0; cch < 4; ++cch) {
          int d = cch * 64 + lane;        // 64-lane stride-1: conflict-free atomics
          atomicAdd(&sm.b.ls[id * DIM + d], xr[d]);
        }
      }
      __syncthreads();
      if (t < NK) {                       // deterministic counts from ids_loc
        int cntk = 0;
        for (int p = 0; p < NK; ++p) cntk += (ids_loc[p] == t) ? 1 : 0;
        pcnt[(size_t)b * NK + t] = (float)cntk;
      }
      float4* ps4 = (float4*)(psum + (size_t)b * NK * DIM);
#pragma unroll
      for (int i = 0; i < 16; ++i) ps4[i * NTHR + t] = ls4[i * NTHR + t];
    }
    gbar(bar);

    // ---- phase C: reduce 256 partials -> means -> hi/lo images + cn (128 blocks) ----
    if (b < NK) {
      const float4* pp = (const float4*)psum;
      float4 s4 = make_float4(0.f, 0.f, 0.f, 0.f);
      for (int p = w * 32; p < w * 32 + 32; ++p) {          // wave w sums 32 partials
        float4 v = pp[((size_t)p * NK + b) * 64 + lane];    // lane -> dims 4l..4l+3
        s4.x += v.x; s4.y += v.y; s4.z += v.z; s4.w += v.w;
      }
      redc4[w * 64 + lane] = s4;
      float cv = (t < NBLK) ? pcnt[(size_t)t * NK + b] : 0.f;
#pragma unroll
      for (int msk = 1; msk < 64; msk <<= 1) cv += __shfl_xor(cv, msk, 64);
      if (lane == 0) sm.c.red[w] = cv;
      __syncthreads();
      if (t < DIM) {
        const float* rc = (const float*)redc4;
        float ssum = 0.f;
#pragma unroll
        for (int ww = 0; ww < 8; ++ww) ssum += rc[ww * 256 + t];
        float cnt = 0.f;
#pragma unroll
        for (int ww = 0; ww < 8; ++ww) cnt += sm.c.red[ww];
        float mean = ssum / cnt;          // NaN for empty cluster, like reference
        unsigned short hh = f2bf(mean);
        unsigned short ll = f2bf(mean - bf2f(hh));
        chi[b * DIM + t] = hh;
        clo[b * DIM + t] = ll;
        float eff = bf2f(hh) + bf2f(ll);
        __syncthreads();
        sm.c.red[t] = eff * eff;
      } else {
        __syncthreads();
        sm.c.red[t] = 0.f;
      }
      __syncthreads();
      for (int st = 256; st > 0; st >>= 1) { if (t < st) sm.c.red[t] += sm.c.red[t + st]; __syncthreads(); }
      if (t == 0) cn[b] = sm.c.red[0];
    }
    gbar(bar);
  }

  // ---------------- final: loss (log-softmax + CE), deterministic reduce ----------------
  {
    f4v acc[4][2];
    gemm_core(sm, b, t, xh, xl, chi, clo, cn, acc);
#pragma unroll
    for (int i = 0; i < 4; ++i) {
#pragma unroll
      for (int r = 0; r < 4; ++r) {
        int prow = wr * 64 + i * 16 + g * 4 + r;
        float m = -1e30f;
#pragma unroll
        for (int j = 0; j < 2; ++j) m = fmaxf(m, acc[i][j][r]);
#pragma unroll
        for (int msk = 1; msk < 16; msk <<= 1) m = fmaxf(m, __shfl_xor(m, msk, 64));
        if (lr == 0) sm.a.redd[prow * 4 + wc] = m;
      }
    }
    __syncthreads();
    if (t < NK) {
      float m = sm.a.redd[t * 4];
#pragma unroll
      for (int q = 1; q < 4; ++q) m = fmaxf(m, sm.a.redd[t * 4 + q]);
      sm.a.gmaxs[t] = m;
      sm.a.labis[t] = ids[pbase + t];
    }
    __syncthreads();
#pragma unroll
    for (int i = 0; i < 4; ++i) {
#pragma unroll
      for (int r = 0; r < 4; ++r) {
        int prow = wr * 64 + i * 16 + g * 4 + r;
        float m = sm.a.gmaxs[prow];
        int lab = sm.a.labis[prow];
        float s = 0.f;
#pragma unroll
        for (int j = 0; j < 2; ++j) {
          int col = wc * 32 + j * 16 + lr;
          float v = acc[i][j][r];
          s += expf(v - m);
          if (col == lab) sm.a.labvs[prow] = v;
        }
#pragma unroll
        for (int msk = 1; msk < 16; msk <<= 1) s += __shfl_xor(s, msk, 64);
        if (lr == 0) sm.a.redd[prow * 4 + wc] = s;
      }
    }
    __syncthreads();
    if (t < NK) {
      float se = sm.a.redd[t * 4] + sm.a.redd[t * 4 + 1] + sm.a.redd[t * 4 + 2] + sm.a.redd[t * 4 + 3];
      float lse = sm.a.gmaxs[t] + logf(se);
      sm.a.gmaxs[t] = lse - sm.a.labvs[t];
    }
    __syncthreads();
    if (t == 0) {
      float tot = 0.f;
      for (int q = 0; q < NK; ++q) tot += sm.a.gmaxs[q];
      outp[b] = tot;
    }
  }
  gbar(bar);
  if (b == 0) {
    sm.c.red[t] = (t < NBLK) ? outp[t] : 0.f;
    __syncthreads();
    for (int s = 256; s > 0; s >>= 1) { if (t < s) sm.c.red[t] += sm.c.red[t + s]; __syncthreads(); }
    if (t == 0) out[0] = sm.c.red[0] * (1.0f / (float)NPTS);
  }
}

extern "C" void kernel_launch(void* const* d_in, const int* in_sizes, int n_in,
                              void* d_out, int out_size, void* d_ws, size_t ws_size,
                              hipStream_t stream) {
  const float* x        = (const float*)d_in[0];
  const int*   init_idx = (const int*)d_in[1];
  float* out = (float*)d_out;
  char* ws = (char*)d_ws;

  // ws layout (bytes):
  ushort_t* xh  = (ushort_t*)(ws);                    // 16777216
  ushort_t* xl  = (ushort_t*)(ws + 16777216);         // 16777216
  ushort_t* chi = (ushort_t*)(ws + 33554432);         // 65536
  ushort_t* clo = (ushort_t*)(ws + 33619968);         // 65536
  float* cn   = (float*)(ws + 33685504);              // 512
  int*   ids  = (int*)(ws + 33686016);                // 131072
  float* psum = (float*)(ws + 33817088);              // 256*128*256*4 = 33554432
  float* pcnt = (float*)(ws + 67371520);              // 256*128*4 = 131072
  float* outp = (float*)(ws + 67502592);              // 1024
  unsigned* bar = (unsigned*)(ws + 67503616);         // 256

  // reset grid-barrier state every launch (graph replays include this node)
  hipMemsetAsync(bar, 0, 256, stream);
  kmeans_fused<<<dim3(NBLK), dim3(NTHR), 0, stream>>>(
      x, init_idx, xh, xl, chi, clo, cn, ids, psum, pcnt, outp, bar, out);
}

// Round 6
// 12935.355 us; speedup vs baseline: 1.2811x; 1.2811x over previous
//
#include <hip/hip_runtime.h>
#include <cstdint>

#define NPTS 32768
#define DIM  256
#define NK   128
#define NITER 100
#define NBLK 256
#define NTHR 512

typedef unsigned short ushort_t;
typedef __attribute__((ext_vector_type(8))) short s8v;   // 8 bf16 in 4 VGPRs
typedef __attribute__((ext_vector_type(4))) float f4v;   // MFMA accumulator

__device__ __forceinline__ unsigned short f2bf(float f) {
  unsigned u = __float_as_uint(f);
  u += 0x7fffu + ((u >> 16) & 1u);      // RTNE
  return (unsigned short)(u >> 16);
}
__device__ __forceinline__ float bf2f(unsigned short b) {
  return __uint_as_float(((unsigned)b) << 16);
}

// ---- distributed-flag grid barrier ----
// flags[b*16]: per-block arrive word (64B padded, no RMW contention).
// ggen: global generation word. Block 0 aggregates (threads 1..255 poll one
// flag each, coalesced), then publishes ggen; others spin on ggen (read-only).
// Fence structure identical to the proven central-counter version:
// __syncthreads() drains each wave's stores to L2, leader __threadfence()
// writes back L2 (release); after wake, leader __threadfence() invalidates
// (acquire) before __syncthreads() releases the block.
__device__ __forceinline__ void gbar(unsigned* flags, unsigned* ggen, unsigned gen) {
  __syncthreads();                        // all block stores drained to L2
  if (threadIdx.x == 0) __threadfence();  // L2 writeback: publish block's writes
  __syncthreads();
  if (blockIdx.x == 0) {
    const int t = threadIdx.x;
    if (t >= 1 && t < NBLK) {
      while (__hip_atomic_load(&flags[t * 16], __ATOMIC_RELAXED, __HIP_MEMORY_SCOPE_AGENT) < gen)
        __builtin_amdgcn_s_sleep(1);
    }
    __syncthreads();
    if (t == 0) {
      __threadfence();                    // acquire: invalidate stale cached lines
      __hip_atomic_store(ggen, gen, __ATOMIC_RELEASE, __HIP_MEMORY_SCOPE_AGENT);
    }
    __syncthreads();
  } else {
    if (threadIdx.x == 0) {
      __hip_atomic_store(&flags[blockIdx.x * 16], gen, __ATOMIC_RELEASE, __HIP_MEMORY_SCOPE_AGENT);
      while (__hip_atomic_load(ggen, __ATOMIC_RELAXED, __HIP_MEMORY_SCOPE_AGENT) < gen)
        __builtin_amdgcn_s_sleep(1);
      __threadfence();                    // acquire
    }
    __syncthreads();
  }
}

// LDS overlay: A = assign GEMM, B = update accumulator, C = small reduces
union SMu {
  struct {
    s8v bufs[4][2048];        // XH, XL, CH, CL half-D tiles, 32 KB each = 128 KB
    float cns[NK];
    float redd[NK * 4];
    int   redk[NK * 4];
    float gmaxs[NK];
    float labvs[NK];
    int   labis[NK];
  } a;
  struct {
    float ls[NK * DIM];       // 128 KB fp32 partial sums (aliases bufs exactly)
  } b;
  struct {
    float red[NTHR];
  } c;
};

// 8-wave (2 row x 4 col) 3-pass hi/lo bf16 MFMA GEMM: acc[i][j][r] = x_p . c_k
__device__ __forceinline__ void gemm_core(
    SMu& sm, int b, int t,
    const ushort_t* __restrict__ xh, const ushort_t* __restrict__ xl,
    const ushort_t* __restrict__ chi, const ushort_t* __restrict__ clo,
    const float* __restrict__ cn, f4v (&acc)[4][2]) {
  const int lane = t & 63;
  const int w    = t >> 6;
  const int wr   = w >> 2, wc = w & 3;    // 2x4 wave grid: 64 pts x 32 clusters each
  const int g    = lane >> 4, lr = lane & 15;
  const int pbase = b * 128;

  if (t < NK) sm.a.cns[t] = cn[t];

  const f4v zero = {0.f, 0.f, 0.f, 0.f};
#pragma unroll
  for (int i = 0; i < 4; ++i)
#pragma unroll
    for (int j = 0; j < 2; ++j) acc[i][j] = zero;

  const int swz = (lr & 7) << 4;
  int a_off[4], b_off[2];
#pragma unroll
  for (int i = 0; i < 4; ++i) a_off[i] = (wr * 64 + i * 16 + lr) * 256 + g * 16;
#pragma unroll
  for (int j = 0; j < 2; ++j) b_off[j] = (wc * 32 + j * 16 + lr) * 256 + g * 16;

  const ushort_t* srcs[4];
  srcs[0] = xh + pbase * DIM;
  srcs[1] = xl + pbase * DIM;
  srcs[2] = chi;
  srcs[3] = clo;

  for (int h = 0; h < 2; ++h) {           // two D-halves of 128
    __syncthreads();
#pragma unroll
    for (int bb = 0; bb < 4; ++bb) {
      const char* sp = (const char*)srcs[bb];
      char* dp = (char*)sm.a.bufs[bb];
#pragma unroll
      for (int i = 0; i < 4; ++i) {
        int gg = i * NTHR + t;            // granule within 32KB buffer
        int row = gg >> 4, whb = (gg & 15) * 16;
        s8v v = *(const s8v*)(sp + row * 512 + h * 256 + whb);
        *(s8v*)(dp + ((gg * 16) ^ ((row & 7) << 4))) = v;
      }
    }
    __syncthreads();
#pragma unroll
    for (int kk = 0; kk < 4; ++kk) {      // K=128 per half, 4 steps of 32
      s8v ah[4], al[4], bh[2], bl[2];
#pragma unroll
      for (int i = 0; i < 4; ++i) {
        int o = (a_off[i] + kk * 64) ^ swz;
        ah[i] = *(const s8v*)((const char*)sm.a.bufs[0] + o);
        al[i] = *(const s8v*)((const char*)sm.a.bufs[1] + o);
      }
#pragma unroll
      for (int j = 0; j < 2; ++j) {
        int o = (b_off[j] + kk * 64) ^ swz;
        bh[j] = *(const s8v*)((const char*)sm.a.bufs[2] + o);
        bl[j] = *(const s8v*)((const char*)sm.a.bufs[3] + o);
      }
#pragma unroll
      for (int i = 0; i < 4; ++i)
#pragma unroll
        for (int j = 0; j < 2; ++j) {
          acc[i][j] = __builtin_amdgcn_mfma_f32_16x16x32_bf16(ah[i], bh[j], acc[i][j], 0, 0, 0);
          acc[i][j] = __builtin_amdgcn_mfma_f32_16x16x32_bf16(ah[i], bl[j], acc[i][j], 0, 0, 0);
          acc[i][j] = __builtin_amdgcn_mfma_f32_16x16x32_bf16(al[i], bh[j], acc[i][j], 0, 0, 0);
        }
    }
  }
}

__global__ __launch_bounds__(NTHR, 1) void kmeans_fused(
    const float* __restrict__ x, const int* __restrict__ init_idx,
    ushort_t* __restrict__ xh, ushort_t* __restrict__ xl,
    ushort_t* __restrict__ chi, ushort_t* __restrict__ clo,
    float* __restrict__ cn, int* __restrict__ ids,
    float* __restrict__ psum, float* __restrict__ pcnt,
    float* __restrict__ outp, unsigned* __restrict__ flags,
    unsigned* __restrict__ ggen, float* __restrict__ out) {
  __shared__ SMu sm;
  __shared__ int ids_loc[NK];
  __shared__ float4 redc4[8 * 64];        // phase-C cross-wave partials (8 KB)

  const int b = blockIdx.x;
  const int t = threadIdx.x;
  const int lane = t & 63;
  const int w  = t >> 6;
  const int wr = w >> 2, wc = w & 3;
  const int g  = lane >> 4, lr = lane & 15;
  const int pbase = b * 128;
  unsigned gen = 1;

  // ---------------- prep: x -> bf16 hi/lo images (once) ----------------
  for (int i = 0; i < 8; ++i) {
    int gg = b * 4096 + i * NTHR + t;     // 16B out-granule = 8 elems
    const float4* src = (const float4*)x + gg * 2;
    float4 fa = src[0], fb = src[1];
    float vv[8] = {fa.x, fa.y, fa.z, fa.w, fb.x, fb.y, fb.z, fb.w};
    s8v vh, vl;
#pragma unroll
    for (int j = 0; j < 8; ++j) {
      unsigned short hh = f2bf(vv[j]);
      vh[j] = (short)hh;
      vl[j] = (short)f2bf(vv[j] - bf2f(hh));
    }
    ((s8v*)xh)[gg] = vh;
    ((s8v*)xl)[gg] = vl;
  }

  // ---------------- init: c0 = x[init_idx] -> hi/lo + cn ----------------
  if (b < NK) {
    float eff = 0.f;
    if (t < DIM) {
      float v = x[init_idx[b] * DIM + t];
      unsigned short hh = f2bf(v);
      unsigned short ll = f2bf(v - bf2f(hh));
      chi[b * DIM + t] = hh;
      clo[b * DIM + t] = ll;
      eff = bf2f(hh) + bf2f(ll);
    }
    sm.c.red[t] = eff * eff;
    __syncthreads();
    for (int s = 256; s > 0; s >>= 1) { if (t < s) sm.c.red[t] += sm.c.red[t + s]; __syncthreads(); }
    if (t == 0) cn[b] = sm.c.red[0];
  }
  gbar(flags, ggen, gen); ++gen;

  // ---------------- main loop: 100 x (assign -> update-partial | reduce) ----------------
  for (int it = 0; it < NITER; ++it) {
    // ---- phase A: assign (ids stay block-local) ----
    {
      f4v acc[4][2];
      gemm_core(sm, b, t, xh, xl, chi, clo, cn, acc);
      // D layout: col(cluster) = lane&15, row(point in 16x16) = (lane>>4)*4 + reg
#pragma unroll
      for (int i = 0; i < 4; ++i) {
#pragma unroll
        for (int r = 0; r < 4; ++r) {
          int prow = wr * 64 + i * 16 + g * 4 + r;
          float bd = 1e30f; int bk = 0;
#pragma unroll
          for (int j = 0; j < 2; ++j) {
            int col = wc * 32 + j * 16 + lr;
            float s = sm.a.cns[col] - 2.f * acc[i][j][r];
            if (s < bd || (s == bd && col < bk)) { bd = s; bk = col; }
          }
#pragma unroll
          for (int msk = 1; msk < 16; msk <<= 1) {
            float od = __shfl_xor(bd, msk, 64);
            int   ok = __shfl_xor(bk, msk, 64);
            if (od < bd || (od == bd && ok < bk)) { bd = od; bk = ok; }
          }
          if (lr == 0) { sm.a.redd[prow * 4 + wc] = bd; sm.a.redk[prow * 4 + wc] = bk; }
        }
      }
      __syncthreads();
      if (t < NK) {
        float bd = sm.a.redd[t * 4]; int bk = sm.a.redk[t * 4];
#pragma unroll
        for (int q = 1; q < 4; ++q) {
          float dq = sm.a.redd[t * 4 + q]; int kq = sm.a.redk[t * 4 + q];
          if (dq < bd || (dq == bd && kq < bk)) { bd = dq; bk = kq; }
        }
        ids_loc[t] = bk;
        if (it == NITER - 1) ids[pbase + t] = bk;   // only needed for final loss labels
      }
    }

    // ---- phase B: block-local segment-sum into LDS (no barrier needed after A) ----
    {
      float4* ls4 = (float4*)sm.b.ls;
#pragma unroll
      for (int i = 0; i < 16; ++i) ls4[i * NTHR + t] = make_float4(0.f, 0.f, 0.f, 0.f);
      __syncthreads();
      const float* xb = x + (size_t)pbase * DIM;
      for (int s = 0; s < 16; ++s) {
        int p = s * 8 + w;                // each of 8 waves owns 16 points
        int id = ids_loc[p];
        const float* xr = xb + p * DIM;
#pragma unroll
        for (int cch = 0; cch < 4; ++cch) {
          int d = cch * 64 + lane;        // 64-lane stride-1: conflict-free atomics
          atomicAdd(&sm.b.ls[id * DIM + d], xr[d]);
        }
      }
      __syncthreads();
      if (t < NK) {                       // deterministic counts from ids_loc
        int cntk = 0;
        for (int p = 0; p < NK; ++p) cntk += (ids_loc[p] == t) ? 1 : 0;
        pcnt[(size_t)t * NBLK + b] = (float)cntk;
      }
      // flush transposed: psum[cluster][block][dim] -> phase C reads contiguous
      float4* ps4 = (float4*)psum;
#pragma unroll
      for (int r = 0; r < 16; ++r) {
        int idx = r * NTHR + t;           // [0, 8192) float4 granules
        int k = idx >> 6, d4 = idx & 63;
        ps4[((size_t)k * NBLK + b) * 64 + d4] = ls4[idx];
      }
    }
    gbar(flags, ggen, gen); ++gen;

    // ---- phase C: reduce 256 partials -> means -> hi/lo images + cn (128 blocks) ----
    if (b < NK) {
      const float4* pp = (const float4*)psum;
      float4 s4 = make_float4(0.f, 0.f, 0.f, 0.f);
      for (int p = w * 32; p < w * 32 + 32; ++p) {          // wave w sums 32 partials
        float4 v = pp[((size_t)b * NBLK + p) * 64 + lane];  // contiguous 256KB stream
        s4.x += v.x; s4.y += v.y; s4.z += v.z; s4.w += v.w;
      }
      redc4[w * 64 + lane] = s4;
      float cv = (t < NBLK) ? pcnt[(size_t)b * NBLK + t] : 0.f;
#pragma unroll
      for (int msk = 1; msk < 64; msk <<= 1) cv += __shfl_xor(cv, msk, 64);
      if (lane == 0) sm.c.red[w] = cv;
      __syncthreads();
      if (t < DIM) {
        const float* rc = (const float*)redc4;
        float ssum = 0.f;
#pragma unroll
        for (int ww = 0; ww < 8; ++ww) ssum += rc[ww * 256 + t];
        float cnt = 0.f;
#pragma unroll
        for (int ww = 0; ww < 8; ++ww) cnt += sm.c.red[ww];
        float mean = ssum / cnt;          // NaN for empty cluster, like reference
        unsigned short hh = f2bf(mean);
        unsigned short ll = f2bf(mean - bf2f(hh));
        chi[b * DIM + t] = hh;
        clo[b * DIM + t] = ll;
        float eff = bf2f(hh) + bf2f(ll);
        __syncthreads();
        sm.c.red[t] = eff * eff;
      } else {
        __syncthreads();
        sm.c.red[t] = 0.f;
      }
      __syncthreads();
      for (int st = 256; st > 0; st >>= 1) { if (t < st) sm.c.red[t] += sm.c.red[t + st]; __syncthreads(); }
      if (t == 0) cn[b] = sm.c.red[0];
    }
    gbar(flags, ggen, gen); ++gen;
  }

  // ---------------- final: loss (log-softmax + CE), deterministic reduce ----------------
  {
    f4v acc[4][2];
    gemm_core(sm, b, t, xh, xl, chi, clo, cn, acc);
#pragma unroll
    for (int i = 0; i < 4; ++i) {
#pragma unroll
      for (int r = 0; r < 4; ++r) {
        int prow = wr * 64 + i * 16 + g * 4 + r;
        float m = -1e30f;
#pragma unroll
        for (int j = 0; j < 2; ++j) m = fmaxf(m, acc[i][j][r]);
#pragma unroll
        for (int msk = 1; msk < 16; msk <<= 1) m = fmaxf(m, __shfl_xor(m, msk, 64));
        if (lr == 0) sm.a.redd[prow * 4 + wc] = m;
      }
    }
    __syncthreads();
    if (t < NK) {
      float m = sm.a.redd[t * 4];
#pragma unroll
      for (int q = 1; q < 4; ++q) m = fmaxf(m, sm.a.redd[t * 4 + q]);
      sm.a.gmaxs[t] = m;
      sm.a.labis[t] = ids[pbase + t];
    }
    __syncthreads();
#pragma unroll
    for (int i = 0; i < 4; ++i) {
#pragma unroll
      for (int r = 0; r < 4; ++r) {
        int prow = wr * 64 + i * 16 + g * 4 + r;
        float m = sm.a.gmaxs[prow];
        int lab = sm.a.labis[prow];
        float s = 0.f;
#pragma unroll
        for (int j = 0; j < 2; ++j) {
          int col = wc * 32 + j * 16 + lr;
          float v = acc[i][j][r];
          s += expf(v - m);
          if (col == lab) sm.a.labvs[prow] = v;
        }
#pragma unroll
        for (int msk = 1; msk < 16; msk <<= 1) s += __shfl_xor(s, msk, 64);
        if (lr == 0) sm.a.redd[prow * 4 + wc] = s;
      }
    }
    __syncthreads();
    if (t < NK) {
      float se = sm.a.redd[t * 4] + sm.a.redd[t * 4 + 1] + sm.a.redd[t * 4 + 2] + sm.a.redd[t * 4 + 3];
      float lse = sm.a.gmaxs[t] + logf(se);
      sm.a.gmaxs[t] = lse - sm.a.labvs[t];
    }
    __syncthreads();
    if (t == 0) {
      float tot = 0.f;
      for (int q = 0; q < NK; ++q) tot += sm.a.gmaxs[q];
      outp[b] = tot;
    }
  }
  gbar(flags, ggen, gen); ++gen;
  if (b == 0) {
    sm.c.red[t] = (t < NBLK) ? outp[t] : 0.f;
    __syncthreads();
    for (int s = 256; s > 0; s >>= 1) { if (t < s) sm.c.red[t] += sm.c.red[t + s]; __syncthreads(); }
    if (t == 0) out[0] = sm.c.red[0] * (1.0f / (float)NPTS);
  }
}

extern "C" void kernel_launch(void* const* d_in, const int* in_sizes, int n_in,
                              void* d_out, int out_size, void* d_ws, size_t ws_size,
                              hipStream_t stream) {
  const float* x        = (const float*)d_in[0];
  const int*   init_idx = (const int*)d_in[1];
  float* out = (float*)d_out;
  char* ws = (char*)d_ws;

  // ws layout (bytes):
  ushort_t* xh  = (ushort_t*)(ws);                    // 16777216
  ushort_t* xl  = (ushort_t*)(ws + 16777216);         // 16777216
  ushort_t* chi = (ushort_t*)(ws + 33554432);         // 65536
  ushort_t* clo = (ushort_t*)(ws + 33619968);         // 65536
  float* cn   = (float*)(ws + 33685504);              // 512
  int*   ids  = (int*)(ws + 33686016);                // 131072
  float* psum = (float*)(ws + 33817088);              // 256*128*256*4 = 33554432
  float* pcnt = (float*)(ws + 67371520);              // 128*256*4 = 131072
  float* outp = (float*)(ws + 67502592);              // 1024
  unsigned* flags = (unsigned*)(ws + 67503616);       // 256*64B = 16384
  unsigned* ggen  = (unsigned*)(ws + 67520000);       // 64

  // reset barrier state every launch (graph replays include this node)
  hipMemsetAsync(flags, 0, 16448, stream);
  kmeans_fused<<<dim3(NBLK), dim3(NTHR), 0, stream>>>(
      x, init_idx, xh, xl, chi, clo, cn, ids, psum, pcnt, outp, flags, ggen, out);
}

// Round 7
// 10187.830 us; speedup vs baseline: 1.6265x; 1.2697x over previous
//
#include <hip/hip_runtime.h>
#include <cstdint>

#define NPTS 32768
#define DIM  256
#define NK   128
#define NITER 100
#define NBLK 256
#define NTHR 512

typedef unsigned short ushort_t;
typedef __attribute__((ext_vector_type(8))) short s8v;   // 8 bf16 in 4 VGPRs
typedef __attribute__((ext_vector_type(4))) float f4v;   // MFMA accumulator

__device__ __forceinline__ unsigned short f2bf(float f) {
  unsigned u = __float_as_uint(f);
  u += 0x7fffu + ((u >> 16) & 1u);      // RTNE
  return (unsigned short)(u >> 16);
}
__device__ __forceinline__ float bf2f(unsigned short b) {
  return __uint_as_float(((unsigned)b) << 16);
}

// ---- distributed-flag grid barrier (proven R6 structure) ----
__device__ __forceinline__ void gbar(unsigned* flags, unsigned* ggen, unsigned gen) {
  __syncthreads();                        // all block stores drained
  if (threadIdx.x == 0) __threadfence();  // release: publish block's writes
  __syncthreads();
  if (blockIdx.x == 0) {
    const int t = threadIdx.x;
    if (t >= 1 && t < NBLK) {
      while (__hip_atomic_load(&flags[t * 16], __ATOMIC_RELAXED, __HIP_MEMORY_SCOPE_AGENT) < gen)
        __builtin_amdgcn_s_sleep(1);
    }
    __syncthreads();
    if (t == 0) {
      __threadfence();                    // acquire
      __hip_atomic_store(ggen, gen, __ATOMIC_RELEASE, __HIP_MEMORY_SCOPE_AGENT);
    }
    __syncthreads();
  } else {
    if (threadIdx.x == 0) {
      __hip_atomic_store(&flags[blockIdx.x * 16], gen, __ATOMIC_RELEASE, __HIP_MEMORY_SCOPE_AGENT);
      while (__hip_atomic_load(ggen, __ATOMIC_RELAXED, __HIP_MEMORY_SCOPE_AGENT) < gen)
        __builtin_amdgcn_s_sleep(1);
      __threadfence();                    // acquire
    }
    __syncthreads();
  }
}

// LDS overlay: A = assign GEMM tiles + epilogue scratch, B = update accumulator.
// NOTE: small reduce scratch (redsm) is OUTSIDE the union so phase C cannot
// alias the in-flight DMA prefetch into bufs[0..1].
union SMu {
  struct {
    s8v bufs[4][2048];        // XH, XL, CH, CL half-D tiles, 32 KB each = 128 KB
    float cns[NK];
    float redd[NK * 4];
    int   redk[NK * 4];
    float gmaxs[NK];
    float labvs[NK];
    int   labis[NK];
  } a;
  struct {
    float ls[NK * DIM];       // 128 KB fp32 partial sums (aliases bufs exactly)
  } b;
};

// Stage one 32KB half-D tile via global_load_lds (linear LDS dest, pre-swizzled
// global source). Produces LDS[G] = global[G ^ (row&7)] (granules of 16B),
// identical to the previous swizzled-ds_write image.
__device__ __forceinline__ void stage4(const ushort_t* __restrict__ src, s8v* buf, int h, int t) {
  const int lane = t & 63;
  const int wb = (t >> 6) << 6;           // wave-uniform base granule
#pragma unroll
  for (int i = 0; i < 4; ++i) {
    const int Gb = i * 512 + wb;          // uniform across wave
    const int G  = Gb + lane;             // this lane's LDS granule
    const int Gs = G ^ ((G >> 4) & 7);    // pre-swizzled source granule (same row)
    const char* ga = (const char*)src + (G >> 4) * 512 + h * 256 + (Gs & 15) * 16;
    __builtin_amdgcn_global_load_lds(
        (const __attribute__((address_space(1))) void*)ga,
        (__attribute__((address_space(3))) void*)((char*)buf + Gb * 16),
        16, 0, 0);
  }
}

// 8-wave (2 row x 4 col) 3-pass hi/lo bf16 MFMA GEMM: acc[i][j][r] = x_p . c_k
// If have_x, bufs[0..1] already hold the half-0 x tiles (cross-barrier prefetch).
__device__ __forceinline__ void gemm_core(
    SMu& sm, int t,
    const ushort_t* __restrict__ xhb, const ushort_t* __restrict__ xlb,
    const ushort_t* __restrict__ chi, const ushort_t* __restrict__ clo,
    const float* __restrict__ cn, bool have_x, f4v (&acc)[4][2]) {
  const int lane = t & 63;
  const int w    = t >> 6;
  const int wr   = w >> 2, wc = w & 3;    // 2x4 wave grid: 64 pts x 32 clusters each
  const int g    = lane >> 4, lr = lane & 15;

  if (t < NK) sm.a.cns[t] = cn[t];

  const f4v zero = {0.f, 0.f, 0.f, 0.f};
#pragma unroll
  for (int i = 0; i < 4; ++i)
#pragma unroll
    for (int j = 0; j < 2; ++j) acc[i][j] = zero;

  const int swz = (lr & 7) << 4;
  int a_off[4], b_off[2];
#pragma unroll
  for (int i = 0; i < 4; ++i) a_off[i] = (wr * 64 + i * 16 + lr) * 256 + g * 16;
#pragma unroll
  for (int j = 0; j < 2; ++j) b_off[j] = (wc * 32 + j * 16 + lr) * 256 + g * 16;

  for (int h = 0; h < 2; ++h) {           // two D-halves of 128
    // stage tiles for this half (DMA, fire-and-forget; drained by syncthreads)
    stage4(chi, sm.a.bufs[2], h, t);
    stage4(clo, sm.a.bufs[3], h, t);
    if (h == 1 || !have_x) {
      stage4(xhb, sm.a.bufs[0], h, t);
      stage4(xlb, sm.a.bufs[1], h, t);
    }
    __syncthreads();                      // DMA landed; previous half's reads done
#pragma unroll
    for (int kk = 0; kk < 4; ++kk) {      // K=128 per half, 4 steps of 32
      s8v ah[4], al[4], bh[2], bl[2];
#pragma unroll
      for (int i = 0; i < 4; ++i) {
        int o = (a_off[i] + kk * 64) ^ swz;
        ah[i] = *(const s8v*)((const char*)sm.a.bufs[0] + o);
        al[i] = *(const s8v*)((const char*)sm.a.bufs[1] + o);
      }
#pragma unroll
      for (int j = 0; j < 2; ++j) {
        int o = (b_off[j] + kk * 64) ^ swz;
        bh[j] = *(const s8v*)((const char*)sm.a.bufs[2] + o);
        bl[j] = *(const s8v*)((const char*)sm.a.bufs[3] + o);
      }
#pragma unroll
      for (int i = 0; i < 4; ++i)
#pragma unroll
        for (int j = 0; j < 2; ++j) {
          acc[i][j] = __builtin_amdgcn_mfma_f32_16x16x32_bf16(ah[i], bh[j], acc[i][j], 0, 0, 0);
          acc[i][j] = __builtin_amdgcn_mfma_f32_16x16x32_bf16(ah[i], bl[j], acc[i][j], 0, 0, 0);
          acc[i][j] = __builtin_amdgcn_mfma_f32_16x16x32_bf16(al[i], bh[j], acc[i][j], 0, 0, 0);
        }
    }
    if (h == 0) __syncthreads();          // half-0 reads done before overwrite
  }
}

__global__ __launch_bounds__(NTHR, 1) void kmeans_fused(
    const float* __restrict__ x, const int* __restrict__ init_idx,
    ushort_t* __restrict__ xh, ushort_t* __restrict__ xl,
    ushort_t* __restrict__ chi, ushort_t* __restrict__ clo,
    float* __restrict__ cn, int* __restrict__ ids,
    float* __restrict__ psum, float* __restrict__ pcnt,
    float* __restrict__ outp, unsigned* __restrict__ flags,
    unsigned* __restrict__ ggen, float* __restrict__ out) {
  __shared__ SMu sm;
  __shared__ int ids_loc[NK];
  __shared__ float4 redc4[8 * 64];        // phase-C cross-wave partials (8 KB)
  __shared__ float redsm[NTHR];           // small reduce scratch (outside union!)

  const int b = blockIdx.x;
  const int t = threadIdx.x;
  const int lane = t & 63;
  const int w  = t >> 6;
  const int wr = w >> 2, wc = w & 3;
  const int g  = lane >> 4, lr = lane & 15;
  const int pbase = b * 128;
  const ushort_t* xhb = xh + (size_t)pbase * DIM;
  const ushort_t* xlb = xl + (size_t)pbase * DIM;
  unsigned gen = 1;
  bool have_x = false;

  // ---------------- prep: x -> bf16 hi/lo images (once) ----------------
  for (int i = 0; i < 8; ++i) {
    int gg = b * 4096 + i * NTHR + t;     // 16B out-granule = 8 elems
    const float4* src = (const float4*)x + gg * 2;
    float4 fa = src[0], fb = src[1];
    float vv[8] = {fa.x, fa.y, fa.z, fa.w, fb.x, fb.y, fb.z, fb.w};
    s8v vh, vl;
#pragma unroll
    for (int j = 0; j < 8; ++j) {
      unsigned short hh = f2bf(vv[j]);
      vh[j] = (short)hh;
      vl[j] = (short)f2bf(vv[j] - bf2f(hh));
    }
    ((s8v*)xh)[gg] = vh;
    ((s8v*)xl)[gg] = vl;
  }

  // ---------------- init: c0 = x[init_idx] -> hi/lo + cn ----------------
  if (b < NK) {
    float eff = 0.f;
    if (t < DIM) {
      float v = x[init_idx[b] * DIM + t];
      unsigned short hh = f2bf(v);
      unsigned short ll = f2bf(v - bf2f(hh));
      chi[b * DIM + t] = hh;
      clo[b * DIM + t] = ll;
      eff = bf2f(hh) + bf2f(ll);
    }
    redsm[t] = eff * eff;
    __syncthreads();
    for (int s = 256; s > 0; s >>= 1) { if (t < s) redsm[t] += redsm[t + s]; __syncthreads(); }
    if (t == 0) cn[b] = redsm[0];
  }
  gbar(flags, ggen, gen); ++gen;

  // ---------------- main loop: 100 x (assign -> update-partial | reduce) ----------------
  for (int it = 0; it < NITER; ++it) {
    // ---- phase A: assign (ids stay block-local) ----
    {
      f4v acc[4][2];
      gemm_core(sm, t, xhb, xlb, chi, clo, cn, have_x, acc);
      // D layout: col(cluster) = lane&15, row(point in 16x16) = (lane>>4)*4 + reg
#pragma unroll
      for (int i = 0; i < 4; ++i) {
#pragma unroll
        for (int r = 0; r < 4; ++r) {
          int prow = wr * 64 + i * 16 + g * 4 + r;
          float bd = 1e30f; int bk = 0;
#pragma unroll
          for (int j = 0; j < 2; ++j) {
            int col = wc * 32 + j * 16 + lr;
            float s = sm.a.cns[col] - 2.f * acc[i][j][r];
            if (s < bd || (s == bd && col < bk)) { bd = s; bk = col; }
          }
#pragma unroll
          for (int msk = 1; msk < 16; msk <<= 1) {
            float od = __shfl_xor(bd, msk, 64);
            int   ok = __shfl_xor(bk, msk, 64);
            if (od < bd || (od == bd && ok < bk)) { bd = od; bk = ok; }
          }
          if (lr == 0) { sm.a.redd[prow * 4 + wc] = bd; sm.a.redk[prow * 4 + wc] = bk; }
        }
      }
      __syncthreads();
      if (t < NK) {
        float bd = sm.a.redd[t * 4]; int bk = sm.a.redk[t * 4];
#pragma unroll
        for (int q = 1; q < 4; ++q) {
          float dq = sm.a.redd[t * 4 + q]; int kq = sm.a.redk[t * 4 + q];
          if (dq < bd || (dq == bd && kq < bk)) { bd = dq; bk = kq; }
        }
        ids_loc[t] = bk;
        if (it == NITER - 1) ids[pbase + t] = bk;   // labels for the final loss
      }
    }

    // ---- phase B: block-local segment-sum into LDS (no barrier needed after A) ----
    {
      float4* ls4 = (float4*)sm.b.ls;
#pragma unroll
      for (int i = 0; i < 16; ++i) ls4[i * NTHR + t] = make_float4(0.f, 0.f, 0.f, 0.f);
      __syncthreads();
      const float* xb = x + (size_t)pbase * DIM;
#pragma unroll 4
      for (int s = 0; s < 16; ++s) {
        int p = s * 8 + w;                // each of 8 waves owns 16 points
        int id = ids_loc[p];
        const float* xr = xb + p * DIM;
#pragma unroll
        for (int cch = 0; cch < 4; ++cch) {
          int d = cch * 64 + lane;        // 64-lane stride-1: conflict-free atomics
          atomicAdd(&sm.b.ls[id * DIM + d], xr[d]);
        }
      }
      __syncthreads();
      if (t < NK) {                       // deterministic counts from ids_loc
        int cntk = 0;
        for (int p = 0; p < NK; ++p) cntk += (ids_loc[p] == t) ? 1 : 0;
        pcnt[(size_t)t * NBLK + b] = (float)cntk;
      }
      // flush transposed: psum[cluster][block][dim] -> phase C reads contiguous
      float4* ps4 = (float4*)psum;
#pragma unroll
      for (int r = 0; r < 16; ++r) {
        int idx = r * NTHR + t;           // [0, 8192) float4 granules
        int k = idx >> 6, d4 = idx & 63;
        ps4[((size_t)k * NBLK + b) * 64 + d4] = ls4[idx];
      }
      __syncthreads();                    // all ls reads done before DMA overwrites
      // cross-barrier prefetch: next phase-A half-0 x tiles (completes during C+barriers)
      stage4(xhb, sm.a.bufs[0], 0, t);
      stage4(xlb, sm.a.bufs[1], 0, t);
      have_x = true;
    }
    gbar(flags, ggen, gen); ++gen;

    // ---- phase C: reduce 256 partials -> means -> hi/lo images + cn (128 blocks) ----
    if (b < NK) {
      const float4* pp = (const float4*)psum;
      float4 s4 = make_float4(0.f, 0.f, 0.f, 0.f);
#pragma unroll 8
      for (int p = w * 32; p < w * 32 + 32; ++p) {          // wave w sums 32 partials
        float4 v = pp[((size_t)b * NBLK + p) * 64 + lane];  // contiguous 256KB stream
        s4.x += v.x; s4.y += v.y; s4.z += v.z; s4.w += v.w;
      }
      redc4[w * 64 + lane] = s4;
      float cv = (t < NBLK) ? pcnt[(size_t)b * NBLK + t] : 0.f;
#pragma unroll
      for (int msk = 1; msk < 64; msk <<= 1) cv += __shfl_xor(cv, msk, 64);
      if (lane == 0) redsm[w] = cv;
      __syncthreads();
      if (t < DIM) {
        const float* rc = (const float*)redc4;
        float ssum = 0.f;
#pragma unroll
        for (int ww = 0; ww < 8; ++ww) ssum += rc[ww * 256 + t];
        float cnt = 0.f;
#pragma unroll
        for (int ww = 0; ww < 8; ++ww) cnt += redsm[ww];
        float mean = ssum / cnt;          // NaN for empty cluster, like reference
        unsigned short hh = f2bf(mean);
        unsigned short ll = f2bf(mean - bf2f(hh));
        chi[b * DIM + t] = hh;
        clo[b * DIM + t] = ll;
        float eff = bf2f(hh) + bf2f(ll);
        __syncthreads();
        redsm[t] = eff * eff;
      } else {
        __syncthreads();
        redsm[t] = 0.f;
      }
      __syncthreads();
      for (int st = 256; st > 0; st >>= 1) { if (t < st) redsm[t] += redsm[t + st]; __syncthreads(); }
      if (t == 0) cn[b] = redsm[0];
    }
    gbar(flags, ggen, gen); ++gen;
  }

  // ---------------- final: loss (log-softmax + CE), deterministic reduce ----------------
  {
    f4v acc[4][2];
    gemm_core(sm, t, xhb, xlb, chi, clo, cn, have_x, acc);
#pragma unroll
    for (int i = 0; i < 4; ++i) {
#pragma unroll
      for (int r = 0; r < 4; ++r) {
        int prow = wr * 64 + i * 16 + g * 4 + r;
        float m = -1e30f;
#pragma unroll
        for (int j = 0; j < 2; ++j) m = fmaxf(m, acc[i][j][r]);
#pragma unroll
        for (int msk = 1; msk < 16; msk <<= 1) m = fmaxf(m, __shfl_xor(m, msk, 64));
        if (lr == 0) sm.a.redd[prow * 4 + wc] = m;
      }
    }
    __syncthreads();
    if (t < NK) {
      float m = sm.a.redd[t * 4];
#pragma unroll
      for (int q = 1; q < 4; ++q) m = fmaxf(m, sm.a.redd[t * 4 + q]);
      sm.a.gmaxs[t] = m;
      sm.a.labis[t] = ids[pbase + t];
    }
    __syncthreads();
#pragma unroll
    for (int i = 0; i < 4; ++i) {
#pragma unroll
      for (int r = 0; r < 4; ++r) {
        int prow = wr * 64 + i * 16 + g * 4 + r;
        float m = sm.a.gmaxs[prow];
        int lab = sm.a.labis[prow];
        float s = 0.f;
#pragma unroll
        for (int j = 0; j < 2; ++j) {
          int col = wc * 32 + j * 16 + lr;
          float v = acc[i][j][r];
          s += expf(v - m);
          if (col == lab) sm.a.labvs[prow] = v;
        }
#pragma unroll
        for (int msk = 1; msk < 16; msk <<= 1) s += __shfl_xor(s, msk, 64);
        if (lr == 0) sm.a.redd[prow * 4 + wc] = s;
      }
    }
    __syncthreads();
    if (t < NK) {
      float se = sm.a.redd[t * 4] + sm.a.redd[t * 4 + 1] + sm.a.redd[t * 4 + 2] + sm.a.redd[t * 4 + 3];
      float lse = sm.a.gmaxs[t] + logf(se);
      sm.a.gmaxs[t] = lse - sm.a.labvs[t];
    }
    __syncthreads();
    if (t == 0) {
      float tot = 0.f;
      for (int q = 0; q < NK; ++q) tot += sm.a.gmaxs[q];
      outp[b] = tot;
    }
  }
  gbar(flags, ggen, gen); ++gen;
  if (b == 0) {
    redsm[t] = (t < NBLK) ? outp[t] : 0.f;
    __syncthreads();
    for (int s = 256; s > 0; s >>= 1) { if (t < s) redsm[t] += redsm[t + s]; __syncthreads(); }
    if (t == 0) out[0] = redsm[0] * (1.0f / (float)NPTS);
  }
}

extern "C" void kernel_launch(void* const* d_in, const int* in_sizes, int n_in,
                              void* d_out, int out_size, void* d_ws, size_t ws_size,
                              hipStream_t stream) {
  const float* x        = (const float*)d_in[0];
  const int*   init_idx = (const int*)d_in[1];
  float* out = (float*)d_out;
  char* ws = (char*)d_ws;

  // ws layout (bytes):
  ushort_t* xh  = (ushort_t*)(ws);                    // 16777216
  ushort_t* xl  = (ushort_t*)(ws + 16777216);         // 16777216
  ushort_t* chi = (ushort_t*)(ws + 33554432);         // 65536
  ushort_t* clo = (ushort_t*)(ws + 33619968);         // 65536
  float* cn   = (float*)(ws + 33685504);              // 512
  int*   ids  = (int*)(ws + 33686016);                // 131072
  float* psum = (float*)(ws + 33817088);              // 256*128*256*4 = 33554432
  float* pcnt = (float*)(ws + 67371520);              // 128*256*4 = 131072
  float* outp = (float*)(ws + 67502592);              // 1024
  unsigned* flags = (unsigned*)(ws + 67503616);       // 256*64B = 16384
  unsigned* ggen  = (unsigned*)(ws + 67520000);       // 64

  // reset barrier state every launch (graph replays include this node)
  hipMemsetAsync(flags, 0, 16448, stream);
  kmeans_fused<<<dim3(NBLK), dim3(NTHR), 0, stream>>>(
      x, init_idx, xh, xl, chi, clo, cn, ids, psum, pcnt, outp, flags, ggen, out);
}

// Round 8
// 8486.215 us; speedup vs baseline: 1.9527x; 1.2005x over previous
//
#include <hip/hip_runtime.h>
#include <cstdint>

#define NPTS 32768
#define DIM  256
#define NK   128
#define NITER 100
#define NBLK 256
#define NTHR 512
#define PAD  33

typedef unsigned short ushort_t;
typedef __attribute__((ext_vector_type(8))) short s8v;   // 8 bf16 in 4 VGPRs
typedef __attribute__((ext_vector_type(4))) float f4v;   // MFMA accumulator

__device__ __forceinline__ unsigned short f2bf(float f) {
  unsigned u = __float_as_uint(f);
  u += 0x7fffu + ((u >> 16) & 1u);      // RTNE
  return (unsigned short)(u >> 16);
}
__device__ __forceinline__ float bf2f(unsigned short b) {
  return __uint_as_float(((unsigned)b) << 16);
}

// agent-scope (LLC-coherent) scalar accesses — bypass non-coherent L1/L2,
// so no __threadfence is needed for data moved through them.
__device__ __forceinline__ void cstore(float* p, float v) {
  __hip_atomic_store(p, v, __ATOMIC_RELAXED, __HIP_MEMORY_SCOPE_AGENT);
}
__device__ __forceinline__ float cload(const float* p) {
  return __hip_atomic_load(p, __ATOMIC_RELAXED, __HIP_MEMORY_SCOPE_AGENT);
}
__device__ __forceinline__ void cstorei(int* p, int v) {
  __hip_atomic_store(p, v, __ATOMIC_RELAXED, __HIP_MEMORY_SCOPE_AGENT);
}
__device__ __forceinline__ int cloadi(const int* p) {
  return __hip_atomic_load(p, __ATOMIC_RELAXED, __HIP_MEMORY_SCOPE_AGENT);
}

// Stage one 32KB half-D tile via global_load_lds (linear LDS dest, pre-swizzled
// global source). Produces LDS[G] = global[G ^ (row&7)] in 16B granules.
__device__ __forceinline__ void stage4(const ushort_t* __restrict__ src, s8v* buf, int h, int t) {
  const int lane = t & 63;
  const int wb = (t >> 6) << 6;           // wave-uniform base granule
#pragma unroll
  for (int i = 0; i < 4; ++i) {
    const int Gb = i * 512 + wb;
    const int G  = Gb + lane;
    const int Gs = G ^ ((G >> 4) & 7);
    const char* ga = (const char*)src + (G >> 4) * 512 + h * 256 + (Gs & 15) * 16;
    __builtin_amdgcn_global_load_lds(
        (const __attribute__((address_space(1))) void*)ga,
        (__attribute__((address_space(3))) void*)((char*)buf + Gb * 16),
        16, 0, 0);
  }
}

// ---- distributed-flag grid barrier. fence=true adds the __threadfence pair
// (needed only when NORMAL loads/stores cross the barrier: centroids, outp).
__device__ __forceinline__ void gbar_core(unsigned* flags, unsigned* ggen, unsigned gen, bool fence) {
  if (blockIdx.x == 0) {
    const int t = threadIdx.x;
    if (t >= 1 && t < NBLK) {
      while (__hip_atomic_load(&flags[t * 16], __ATOMIC_RELAXED, __HIP_MEMORY_SCOPE_AGENT) < gen)
        __builtin_amdgcn_s_sleep(1);
    }
    __syncthreads();
    if (t == 0) {
      if (fence) __threadfence();
      __hip_atomic_store(ggen, gen, __ATOMIC_RELEASE, __HIP_MEMORY_SCOPE_AGENT);
    }
  } else {
    if (threadIdx.x == 0) {
      if (fence) __threadfence();         // release block's normal writes
      __hip_atomic_store(&flags[blockIdx.x * 16], gen, __ATOMIC_RELEASE, __HIP_MEMORY_SCOPE_AGENT);
      while (__hip_atomic_load(ggen, __ATOMIC_RELAXED, __HIP_MEMORY_SCOPE_AGENT) < gen)
        __builtin_amdgcn_s_sleep(1);
      if (fence) __threadfence();         // acquire
    }
  }
  asm volatile("" ::: "memory");
  __syncthreads();
}

__device__ __forceinline__ void gbar_nf(unsigned* flags, unsigned* ggen, unsigned gen) {
  __syncthreads();                        // drains each thread's vmem (incl. sc1 stores)
  gbar_core(flags, ggen, gen, false);
}
__device__ __forceinline__ void gbar_f(unsigned* flags, unsigned* ggen, unsigned gen) {
  __syncthreads();
  gbar_core(flags, ggen, gen, true);
}
// fenced barrier that launches the next GEMM's x half-0 prefetch INSIDE the
// barrier window (after entry-sync, before poll) so the DMA overlaps fence+poll.
__device__ __forceinline__ void gbar_f_pf(unsigned* flags, unsigned* ggen, unsigned gen,
    const ushort_t* xhb, const ushort_t* xlb, s8v (*bufs)[2048], int t) {
  __syncthreads();
  stage4(xhb, bufs[0], 0, t);             // reads immutable xh/xl: safe pre-fence
  stage4(xlb, bufs[1], 0, t);
  gbar_core(flags, ggen, gen, true);
}

struct SMa {
  s8v bufs[4][2048];        // XH, XL, CH, CL half-D tiles, 32 KB each = 128 KB
  float cns[NK];
  float redd[NK * 4];
  int   redk[NK * 4];
  float gmaxs[NK];
  float labvs[NK];
  int   labis[NK];
};

// 8-wave (2 row x 4 col) 3-pass hi/lo bf16 MFMA GEMM: acc[i][j][r] = x_p . c_k
// bufs[0..1] half-0 is ALWAYS prefetched by the preceding gbar_f_pf.
__device__ __forceinline__ void gemm_core(
    SMa& sm, int t,
    const ushort_t* __restrict__ xhb, const ushort_t* __restrict__ xlb,
    const ushort_t* __restrict__ chi, const ushort_t* __restrict__ clo,
    const float* __restrict__ cn, f4v (&acc)[4][2]) {
  const int lane = t & 63;
  const int w    = t >> 6;
  const int wr   = w >> 2, wc = w & 3;    // 2x4 wave grid: 64 pts x 32 clusters each
  const int g    = lane >> 4, lr = lane & 15;

  if (t < NK) sm.cns[t] = cn[t];

  const f4v zero = {0.f, 0.f, 0.f, 0.f};
#pragma unroll
  for (int i = 0; i < 4; ++i)
#pragma unroll
    for (int j = 0; j < 2; ++j) acc[i][j] = zero;

  const int swz = (lr & 7) << 4;
  int a_off[4], b_off[2];
#pragma unroll
  for (int i = 0; i < 4; ++i) a_off[i] = (wr * 64 + i * 16 + lr) * 256 + g * 16;
#pragma unroll
  for (int j = 0; j < 2; ++j) b_off[j] = (wc * 32 + j * 16 + lr) * 256 + g * 16;

  for (int h = 0; h < 2; ++h) {           // two D-halves of 128
    stage4(chi, sm.bufs[2], h, t);
    stage4(clo, sm.bufs[3], h, t);
    if (h == 1) {
      stage4(xhb, sm.bufs[0], h, t);
      stage4(xlb, sm.bufs[1], h, t);
    }
    __syncthreads();                      // DMA landed
#pragma unroll
    for (int kk = 0; kk < 4; ++kk) {      // K=128 per half, 4 steps of 32
      s8v ah[4], al[4], bh[2], bl[2];
#pragma unroll
      for (int i = 0; i < 4; ++i) {
        int o = (a_off[i] + kk * 64) ^ swz;
        ah[i] = *(const s8v*)((const char*)sm.bufs[0] + o);
        al[i] = *(const s8v*)((const char*)sm.bufs[1] + o);
      }
#pragma unroll
      for (int j = 0; j < 2; ++j) {
        int o = (b_off[j] + kk * 64) ^ swz;
        bh[j] = *(const s8v*)((const char*)sm.bufs[2] + o);
        bl[j] = *(const s8v*)((const char*)sm.bufs[3] + o);
      }
#pragma unroll
      for (int i = 0; i < 4; ++i)
#pragma unroll
        for (int j = 0; j < 2; ++j) {
          acc[i][j] = __builtin_amdgcn_mfma_f32_16x16x32_bf16(ah[i], bh[j], acc[i][j], 0, 0, 0);
          acc[i][j] = __builtin_amdgcn_mfma_f32_16x16x32_bf16(ah[i], bl[j], acc[i][j], 0, 0, 0);
          acc[i][j] = __builtin_amdgcn_mfma_f32_16x16x32_bf16(al[i], bh[j], acc[i][j], 0, 0, 0);
        }
    }
    if (h == 0) __syncthreads();          // half-0 reads done before overwrite
  }
}

__global__ __launch_bounds__(NTHR, 1) void kmeans_fused(
    const float* __restrict__ x, const int* __restrict__ init_idx,
    ushort_t* __restrict__ xh, ushort_t* __restrict__ xl,
    ushort_t* __restrict__ chi, ushort_t* __restrict__ clo,
    float* __restrict__ cn, int* __restrict__ ids,
    float* __restrict__ psum, float* __restrict__ pcnt,
    float* __restrict__ outp, unsigned* __restrict__ flags,
    unsigned* __restrict__ ggen, float* __restrict__ out) {
  __shared__ SMa sm;
  __shared__ float accB[NK * PAD];        // 16.5 KB D-split update accumulator
  __shared__ int   idslB[1024];
  __shared__ int   cntB[NK];
  __shared__ float redsm[NTHR];

  const int b = blockIdx.x;
  const int t = threadIdx.x;
  const int lane = t & 63;
  const int w  = t >> 6;
  const int wr = w >> 2, wc = w & 3;
  const int g  = lane >> 4, lr = lane & 15;
  const int pbase = b * 128;
  const ushort_t* xhb = xh + (size_t)pbase * DIM;
  const ushort_t* xlb = xl + (size_t)pbase * DIM;
  unsigned gen = 1;

  // ---------------- prep: x -> bf16 hi/lo images (once) ----------------
  for (int i = 0; i < 8; ++i) {
    int gg = b * 4096 + i * NTHR + t;
    const float4* src = (const float4*)x + gg * 2;
    float4 fa = src[0], fb = src[1];
    float vv[8] = {fa.x, fa.y, fa.z, fa.w, fb.x, fb.y, fb.z, fb.w};
    s8v vh, vl;
#pragma unroll
    for (int j = 0; j < 8; ++j) {
      unsigned short hh = f2bf(vv[j]);
      vh[j] = (short)hh;
      vl[j] = (short)f2bf(vv[j] - bf2f(hh));
    }
    ((s8v*)xh)[gg] = vh;
    ((s8v*)xl)[gg] = vl;
  }

  // ---------------- init: c0 = x[init_idx] -> hi/lo + cn ----------------
  if (b < NK) {
    float eff = 0.f;
    if (t < DIM) {
      float v = x[init_idx[b] * DIM + t];
      unsigned short hh = f2bf(v);
      unsigned short ll = f2bf(v - bf2f(hh));
      chi[b * DIM + t] = hh;
      clo[b * DIM + t] = ll;
      eff = bf2f(hh) + bf2f(ll);
    }
    redsm[t] = eff * eff;
    __syncthreads();
    for (int s = 256; s > 0; s >>= 1) { if (t < s) redsm[t] += redsm[t + s]; __syncthreads(); }
    if (t == 0) cn[b] = redsm[0];
  }
  gbar_f_pf(flags, ggen, gen, xhb, xlb, sm.bufs, t); ++gen;

  // ---------------- main loop ----------------
  for (int it = 0; it < NITER; ++it) {
    // ---- phase A: assign; ids -> global (coherent) ----
    {
      f4v acc[4][2];
      gemm_core(sm, t, xhb, xlb, chi, clo, cn, acc);
#pragma unroll
      for (int i = 0; i < 4; ++i) {
#pragma unroll
        for (int r = 0; r < 4; ++r) {
          int prow = wr * 64 + i * 16 + g * 4 + r;
          float bd = 1e30f; int bk = 0;
#pragma unroll
          for (int j = 0; j < 2; ++j) {
            int col = wc * 32 + j * 16 + lr;
            float s = sm.cns[col] - 2.f * acc[i][j][r];
            if (s < bd || (s == bd && col < bk)) { bd = s; bk = col; }
          }
#pragma unroll
          for (int msk = 1; msk < 16; msk <<= 1) {
            float od = __shfl_xor(bd, msk, 64);
            int   ok = __shfl_xor(bk, msk, 64);
            if (od < bd || (od == bd && ok < bk)) { bd = od; bk = ok; }
          }
          if (lr == 0) { sm.redd[prow * 4 + wc] = bd; sm.redk[prow * 4 + wc] = bk; }
        }
      }
      __syncthreads();
      if (t < NK) {
        float bd = sm.redd[t * 4]; int bk = sm.redk[t * 4];
#pragma unroll
        for (int q = 1; q < 4; ++q) {
          float dq = sm.redd[t * 4 + q]; int kq = sm.redk[t * 4 + q];
          if (dq < bd || (dq == bd && kq < bk)) { bd = dq; bk = kq; }
        }
        cstorei(&ids[pbase + t], bk);
      }
    }
    gbar_nf(flags, ggen, gen); ++gen;

    // ---- phase B: D-split segment-sum (32 pgroups x 8 dgroups) ----
    {
      const int pg = b & 31, dg = b >> 5;
      for (int i = t; i < NK * PAD; i += NTHR) accB[i] = 0.f;
      if (t < NK) cntB[t] = 0;
      idslB[t]        = cloadi(&ids[pg * 1024 + t]);
      idslB[NTHR + t] = cloadi(&ids[pg * 1024 + NTHR + t]);
      __syncthreads();
      if (dg == 0) {
        atomicAdd(&cntB[idslB[t]], 1);
        atomicAdd(&cntB[idslB[NTHR + t]], 1);
      }
      const int qd = t & 7, ps = t >> 3;
      const float* xs = x + (size_t)pg * 1024 * DIM + dg * 32 + qd * 4;
#pragma unroll
      for (int s = 0; s < 16; ++s) {
        int pl = s * 64 + ps;
        int id = idslB[pl];
        float4 v = *(const float4*)(xs + (size_t)pl * DIM);
        atomicAdd(&accB[id * PAD + qd * 4 + 0], v.x);
        atomicAdd(&accB[id * PAD + qd * 4 + 1], v.y);
        atomicAdd(&accB[id * PAD + qd * 4 + 2], v.z);
        atomicAdd(&accB[id * PAD + qd * 4 + 3], v.w);
      }
      __syncthreads();
      const int kl = t >> 5, dl = t & 31;
#pragma unroll
      for (int s2 = 0; s2 < 8; ++s2) {
        int k2 = s2 * 16 + kl;
        cstore(&psum[(((size_t)dg * NK + k2) * 32 + pg) * 32 + dl], accB[k2 * PAD + dl]);
      }
      if (dg == 0 && t < NK)
        cstore(&pcnt[(size_t)pg * NK + t], (float)cntB[t]);
    }
    gbar_nf(flags, ggen, gen); ++gen;

    // ---- phase C: reduce 32 pgroup-partials -> means -> hi/lo + cn (128 blocks) ----
    if (b < NK) {
      const int k = b;
      const int tt = t & 255, hf = t >> 8;
      const int dgc = tt >> 5, dlc = tt & 31;
      float s = 0.f;
#pragma unroll
      for (int p2 = hf * 16; p2 < hf * 16 + 16; ++p2)
        s += cload(&psum[(((size_t)dgc * NK + k) * 32 + p2) * 32 + dlc]);
      redsm[t] = s;
      float cv = 0.f;
      if (t < 32) cv = cload(&pcnt[(size_t)t * NK + k]);
      if (t < 64) {
#pragma unroll
        for (int m = 1; m < 32; m <<= 1) cv += __shfl_xor(cv, m, 64);
      }
      if (t == 0) sm.labvs[0] = cv;
      __syncthreads();
      if (t < DIM) {
        float cnt = sm.labvs[0];
        float mean = (redsm[t] + redsm[t + 256]) / cnt;   // NaN if empty, as ref
        unsigned short hh = f2bf(mean);
        unsigned short ll = f2bf(mean - bf2f(hh));
        chi[k * DIM + t] = hh;
        clo[k * DIM + t] = ll;
        float eff = bf2f(hh) + bf2f(ll);
        __syncthreads();
        redsm[t] = eff * eff;
      } else {
        __syncthreads();
        redsm[t] = 0.f;
      }
      __syncthreads();
      for (int st = 256; st > 0; st >>= 1) { if (t < st) redsm[t] += redsm[t + st]; __syncthreads(); }
      if (t == 0) cn[k] = redsm[0];
    }
    gbar_f_pf(flags, ggen, gen, xhb, xlb, sm.bufs, t); ++gen;
  }

  // ---------------- final: loss (log-softmax + CE), deterministic reduce ----------------
  {
    f4v acc[4][2];
    gemm_core(sm, t, xhb, xlb, chi, clo, cn, acc);
#pragma unroll
    for (int i = 0; i < 4; ++i) {
#pragma unroll
      for (int r = 0; r < 4; ++r) {
        int prow = wr * 64 + i * 16 + g * 4 + r;
        float m = -1e30f;
#pragma unroll
        for (int j = 0; j < 2; ++j) m = fmaxf(m, acc[i][j][r]);
#pragma unroll
        for (int msk = 1; msk < 16; msk <<= 1) m = fmaxf(m, __shfl_xor(m, msk, 64));
        if (lr == 0) sm.redd[prow * 4 + wc] = m;
      }
    }
    __syncthreads();
    if (t < NK) {
      float m = sm.redd[t * 4];
#pragma unroll
      for (int q = 1; q < 4; ++q) m = fmaxf(m, sm.redd[t * 4 + q]);
      sm.gmaxs[t] = m;
      sm.labis[t] = cloadi(&ids[pbase + t]);
    }
    __syncthreads();
#pragma unroll
    for (int i = 0; i < 4; ++i) {
#pragma unroll
      for (int r = 0; r < 4; ++r) {
        int prow = wr * 64 + i * 16 + g * 4 + r;
        float m = sm.gmaxs[prow];
        int lab = sm.labis[prow];
        float s = 0.f;
#pragma unroll
        for (int j = 0; j < 2; ++j) {
          int col = wc * 32 + j * 16 + lr;
          float v = acc[i][j][r];
          s += expf(v - m);
          if (col == lab) sm.labvs[prow] = v;
        }
#pragma unroll
        for (int msk = 1; msk < 16; msk <<= 1) s += __shfl_xor(s, msk, 64);
        if (lr == 0) sm.redd[prow * 4 + wc] = s;
      }
    }
    __syncthreads();
    if (t < NK) {
      float se = sm.redd[t * 4] + sm.redd[t * 4 + 1] + sm.redd[t * 4 + 2] + sm.redd[t * 4 + 3];
      float lse = sm.gmaxs[t] + logf(se);
      sm.gmaxs[t] = lse - sm.labvs[t];
    }
    __syncthreads();
    if (t == 0) {
      float tot = 0.f;
      for (int q = 0; q < NK; ++q) tot += sm.gmaxs[q];
      outp[b] = tot;
    }
  }
  gbar_f(flags, ggen, gen); ++gen;
  if (b == 0) {
    redsm[t] = (t < NBLK) ? outp[t] : 0.f;
    __syncthreads();
    for (int s = 256; s > 0; s >>= 1) { if (t < s) redsm[t] += redsm[t + s]; __syncthreads(); }
    if (t == 0) out[0] = redsm[0] * (1.0f / (float)NPTS);
  }
}

extern "C" void kernel_launch(void* const* d_in, const int* in_sizes, int n_in,
                              void* d_out, int out_size, void* d_ws, size_t ws_size,
                              hipStream_t stream) {
  const float* x        = (const float*)d_in[0];
  const int*   init_idx = (const int*)d_in[1];
  float* out = (float*)d_out;
  char* ws = (char*)d_ws;

  // ws layout (bytes):
  ushort_t* xh  = (ushort_t*)(ws);                    // 16777216
  ushort_t* xl  = (ushort_t*)(ws + 16777216);         // 16777216
  ushort_t* chi = (ushort_t*)(ws + 33554432);         // 65536
  ushort_t* clo = (ushort_t*)(ws + 33619968);         // 65536
  float* cn   = (float*)(ws + 33685504);              // 512
  int*   ids  = (int*)(ws + 33686016);                // 131072
  float* psum = (float*)(ws + 33817088);              // 8*128*32*32*4 = 4194304
  float* pcnt = (float*)(ws + 67371520);              // 32*128*4 = 16384
  float* outp = (float*)(ws + 67502592);              // 1024
  unsigned* flags = (unsigned*)(ws + 67503616);       // 256*64B = 16384
  unsigned* ggen  = (unsigned*)(ws + 67520000);       // 64

  // reset barrier state every launch (graph replays include this node)
  hipMemsetAsync(flags, 0, 16448, stream);
  kmeans_fused<<<dim3(NBLK), dim3(NTHR), 0, stream>>>(
      x, init_idx, xh, xl, chi, clo, cn, ids, psum, pcnt, outp, flags, ggen, out);
}

// Round 9
// 6975.524 us; speedup vs baseline: 2.3756x; 1.2166x over previous
//
#include <hip/hip_runtime.h>
#include <cstdint>

#define NPTS 32768
#define DIM  256
#define NK   128
#define NITER 100
#define NBLK 256
#define NTHR 512
#define PAD  33

typedef unsigned short ushort_t;
typedef unsigned long long ull_t;
typedef __attribute__((ext_vector_type(8))) short s8v;   // 8 bf16 in 4 VGPRs
typedef __attribute__((ext_vector_type(4))) float f4v;   // MFMA accumulator

__device__ __forceinline__ unsigned short f2bf(float f) {
  unsigned u = __float_as_uint(f);
  u += 0x7fffu + ((u >> 16) & 1u);      // RTNE
  return (unsigned short)(u >> 16);
}
__device__ __forceinline__ float bf2f(unsigned short b) {
  return __uint_as_float(((unsigned)b) << 16);
}

// agent-scope (LLC-coherent) accesses — bypass non-coherent L1/L2, so NO
// __threadfence is needed for data moved through them (proven R8: ids/psum).
__device__ __forceinline__ void cstore(float* p, float v) {
  __hip_atomic_store(p, v, __ATOMIC_RELAXED, __HIP_MEMORY_SCOPE_AGENT);
}
__device__ __forceinline__ float cload(const float* p) {
  return __hip_atomic_load(p, __ATOMIC_RELAXED, __HIP_MEMORY_SCOPE_AGENT);
}
__device__ __forceinline__ void cstorei(int* p, int v) {
  __hip_atomic_store(p, v, __ATOMIC_RELAXED, __HIP_MEMORY_SCOPE_AGENT);
}
__device__ __forceinline__ int cloadi(const int* p) {
  return __hip_atomic_load(p, __ATOMIC_RELAXED, __HIP_MEMORY_SCOPE_AGENT);
}
__device__ __forceinline__ void cstore64(ull_t* p, ull_t v) {
  __hip_atomic_store(p, v, __ATOMIC_RELAXED, __HIP_MEMORY_SCOPE_AGENT);
}
__device__ __forceinline__ ull_t cload64(const ull_t* p) {
  return __hip_atomic_load(p, __ATOMIC_RELAXED, __HIP_MEMORY_SCOPE_AGENT);
}

// Stage one 32KB half-D x tile via global_load_lds (linear LDS dest,
// pre-swizzled global source). LDS[G] = global[G ^ (row&7)], 16B granules.
__device__ __forceinline__ void stage4(const ushort_t* __restrict__ src, s8v* buf, int h, int t) {
  const int lane = t & 63;
  const int wb = (t >> 6) << 6;           // wave-uniform base granule
#pragma unroll
  for (int i = 0; i < 4; ++i) {
    const int Gb = i * 512 + wb;
    const int G  = Gb + lane;
    const int Gs = G ^ ((G >> 4) & 7);
    const char* ga = (const char*)src + (G >> 4) * 512 + h * 256 + (Gs & 15) * 16;
    __builtin_amdgcn_global_load_lds(
        (const __attribute__((address_space(1))) void*)ga,
        (__attribute__((address_space(3))) void*)((char*)buf + Gb * 16),
        16, 0, 0);
  }
}

// Stage centroid hi/lo half-D tiles from the packed coherent image.
// cpk[k*128 + u] = dims {2u,2u+1}: hh0 | ll0<<16 | hh1<<32 | ll1<<48.
// Writes the same swizzled LDS image as stage4 would.
__device__ __forceinline__ void stage_c(const ull_t* __restrict__ cpk,
                                        s8v* bh, s8v* bl, int h, int t) {
#pragma unroll
  for (int i = 0; i < 4; ++i) {
    const int G = i * NTHR + t;           // granule id [0,2048)
    const int k = G >> 4, gcol = G & 15;
    const int sc = gcol ^ (k & 7);        // swizzled source column
    const ull_t* src = cpk + (size_t)k * 128 + h * 64 + sc * 4;
    ull_t w0 = cload64(src + 0), w1 = cload64(src + 1);
    ull_t w2 = cload64(src + 2), w3 = cload64(src + 3);
    s8v vh, vl;
    vh[0] = (short)w0; vl[0] = (short)(w0 >> 16); vh[1] = (short)(w0 >> 32); vl[1] = (short)(w0 >> 48);
    vh[2] = (short)w1; vl[2] = (short)(w1 >> 16); vh[3] = (short)(w1 >> 32); vl[3] = (short)(w1 >> 48);
    vh[4] = (short)w2; vl[4] = (short)(w2 >> 16); vh[5] = (short)(w2 >> 32); vl[5] = (short)(w2 >> 48);
    vh[6] = (short)w3; vl[6] = (short)(w3 >> 16); vh[7] = (short)(w3 >> 32); vl[7] = (short)(w3 >> 48);
    *(s8v*)((char*)bh + G * 16) = vh;
    *(s8v*)((char*)bl + G * 16) = vl;
  }
}

// ---- all-to-all 1-hop grid barrier: leader stores own padded flag; threads
// 0..255 each poll one flag. No aggregator, no publish word, no fences.
// Entry __syncthreads drains vmcnt -> all LLC-direct stores are visible.
__device__ __forceinline__ void gbar(unsigned* flags, unsigned gen) {
  __syncthreads();
  if (threadIdx.x == 0)
    __hip_atomic_store(&flags[blockIdx.x * 16], gen, __ATOMIC_RELAXED, __HIP_MEMORY_SCOPE_AGENT);
  if (threadIdx.x < NBLK) {
    while (__hip_atomic_load(&flags[threadIdx.x * 16], __ATOMIC_RELAXED, __HIP_MEMORY_SCOPE_AGENT) < gen)
      __builtin_amdgcn_s_sleep(1);
  }
  asm volatile("" ::: "memory");
  __syncthreads();
}
// barrier that issues next GEMM's x half-0 DMA prefetch inside the window
__device__ __forceinline__ void gbar_pf(unsigned* flags, unsigned gen,
    const ushort_t* xhb, const ushort_t* xlb, s8v (*bufs)[2048], int t) {
  __syncthreads();
  stage4(xhb, bufs[0], 0, t);             // own immutable tile: race-free
  stage4(xlb, bufs[1], 0, t);
  if (t == 0)
    __hip_atomic_store(&flags[blockIdx.x * 16], gen, __ATOMIC_RELAXED, __HIP_MEMORY_SCOPE_AGENT);
  if (t < NBLK) {
    while (__hip_atomic_load(&flags[t * 16], __ATOMIC_RELAXED, __HIP_MEMORY_SCOPE_AGENT) < gen)
      __builtin_amdgcn_s_sleep(1);
  }
  asm volatile("" ::: "memory");
  __syncthreads();
}

struct SMa {
  s8v bufs[4][2048];        // XH, XL, CH, CL half-D tiles, 32 KB each = 128 KB
  float cns[NK];
  float redd[NK * 4];
  int   redk[NK * 4];
  float gmaxs[NK];
  float labvs[NK];
  int   labis[NK];
};

// 8-wave (2x4) 3-pass hi/lo bf16 MFMA GEMM: acc[i][j][r] = x_p . c_k.
// bufs[0..1] half-0 is ALWAYS prefetched by the preceding gbar_pf.
__device__ __forceinline__ void gemm_core(
    SMa& sm, int t,
    const ushort_t* __restrict__ xhb, const ushort_t* __restrict__ xlb,
    const ull_t* __restrict__ cpk, const float* __restrict__ cn, f4v (&acc)[4][2]) {
  const int lane = t & 63;
  const int w    = t >> 6;
  const int wr   = w >> 2, wc = w & 3;    // 2x4 wave grid: 64 pts x 32 clusters
  const int g    = lane >> 4, lr = lane & 15;

  if (t < NK) sm.cns[t] = cload(&cn[t]);

  const f4v zero = {0.f, 0.f, 0.f, 0.f};
#pragma unroll
  for (int i = 0; i < 4; ++i)
#pragma unroll
    for (int j = 0; j < 2; ++j) acc[i][j] = zero;

  const int swz = (lr & 7) << 4;
  int a_off[4], b_off[2];
#pragma unroll
  for (int i = 0; i < 4; ++i) a_off[i] = (wr * 64 + i * 16 + lr) * 256 + g * 16;
#pragma unroll
  for (int j = 0; j < 2; ++j) b_off[j] = (wc * 32 + j * 16 + lr) * 256 + g * 16;

  for (int h = 0; h < 2; ++h) {           // two D-halves of 128
    if (h == 1) {                         // issue DMA first for overlap
      stage4(xhb, sm.bufs[0], 1, t);
      stage4(xlb, sm.bufs[1], 1, t);
    }
    stage_c(cpk, sm.bufs[2], sm.bufs[3], h, t);
    __syncthreads();                      // DMA + cloads + ds_writes landed
#pragma unroll
    for (int kk = 0; kk < 4; ++kk) {      // K=128 per half, 4 steps of 32
      s8v ah[4], al[4], bh[2], bl[2];
#pragma unroll
      for (int i = 0; i < 4; ++i) {
        int o = (a_off[i] + kk * 64) ^ swz;
        ah[i] = *(const s8v*)((const char*)sm.bufs[0] + o);
        al[i] = *(const s8v*)((const char*)sm.bufs[1] + o);
      }
#pragma unroll
      for (int j = 0; j < 2; ++j) {
        int o = (b_off[j] + kk * 64) ^ swz;
        bh[j] = *(const s8v*)((const char*)sm.bufs[2] + o);
        bl[j] = *(const s8v*)((const char*)sm.bufs[3] + o);
      }
#pragma unroll
      for (int i = 0; i < 4; ++i)
#pragma unroll
        for (int j = 0; j < 2; ++j) {
          acc[i][j] = __builtin_amdgcn_mfma_f32_16x16x32_bf16(ah[i], bh[j], acc[i][j], 0, 0, 0);
          acc[i][j] = __builtin_amdgcn_mfma_f32_16x16x32_bf16(ah[i], bl[j], acc[i][j], 0, 0, 0);
          acc[i][j] = __builtin_amdgcn_mfma_f32_16x16x32_bf16(al[i], bh[j], acc[i][j], 0, 0, 0);
        }
    }
    if (h == 0) __syncthreads();          // half-0 reads done before overwrite
  }
}

__global__ __launch_bounds__(NTHR, 1) void kmeans_fused(
    const float* __restrict__ x, const int* __restrict__ init_idx,
    ushort_t* __restrict__ xh, ushort_t* __restrict__ xl,
    ull_t* __restrict__ cpk, float* __restrict__ cn, int* __restrict__ ids,
    float* __restrict__ psum, float* __restrict__ pcnt,
    float* __restrict__ outp, unsigned* __restrict__ flags,
    float* __restrict__ out) {
  __shared__ SMa sm;
  __shared__ float accB[NK * PAD];        // 16.5 KB D-split update accumulator
  __shared__ int   idslB[1024];
  __shared__ int   cntB[NK];
  __shared__ float redsm[NTHR];
  __shared__ ushort_t hsm[DIM], lsm[DIM];
  __shared__ float cntsh;

  const int b = blockIdx.x;
  const int t = threadIdx.x;
  const int lane = t & 63;
  const int w  = t >> 6;
  const int wr = w >> 2, wc = w & 3;
  const int g  = lane >> 4, lr = lane & 15;
  const int pbase = b * 128;
  const ushort_t* xhb = xh + (size_t)pbase * DIM;
  const ushort_t* xlb = xl + (size_t)pbase * DIM;
  unsigned gen = 1;

  // ---------------- prep: x -> bf16 hi/lo images (own tile only) ----------------
  for (int i = 0; i < 8; ++i) {
    int gg = b * 4096 + i * NTHR + t;
    const float4* src = (const float4*)x + gg * 2;
    float4 fa = src[0], fb = src[1];
    float vv[8] = {fa.x, fa.y, fa.z, fa.w, fb.x, fb.y, fb.z, fb.w};
    s8v vh, vl;
#pragma unroll
    for (int j = 0; j < 8; ++j) {
      unsigned short hh = f2bf(vv[j]);
      vh[j] = (short)hh;
      vl[j] = (short)f2bf(vv[j] - bf2f(hh));
    }
    ((s8v*)xh)[gg] = vh;
    ((s8v*)xl)[gg] = vl;
  }

  // ---------------- init: c0 = x[init_idx] -> packed image + cn ----------------
  if (b < NK) {
    float eff = 0.f;
    if (t < DIM) {
      float v = x[init_idx[b] * DIM + t];
      unsigned short hh = f2bf(v);
      unsigned short ll = f2bf(v - bf2f(hh));
      hsm[t] = hh; lsm[t] = ll;
      eff = bf2f(hh) + bf2f(ll);
    }
    __syncthreads();
    redsm[t] = eff * eff;
    if (t < NK) {
      ull_t wv = (ull_t)hsm[2 * t] | ((ull_t)lsm[2 * t] << 16)
               | ((ull_t)hsm[2 * t + 1] << 32) | ((ull_t)lsm[2 * t + 1] << 48);
      cstore64(&cpk[(size_t)b * 128 + t], wv);
    }
    __syncthreads();
    for (int s = 256; s > 0; s >>= 1) { if (t < s) redsm[t] += redsm[t + s]; __syncthreads(); }
    if (t == 0) cstore(&cn[b], redsm[0]);
  }
  gbar_pf(flags, gen, xhb, xlb, sm.bufs, t); ++gen;

  // ---------------- main loop ----------------
  for (int it = 0; it < NITER; ++it) {
    // ---- phase A: assign; ids -> LLC ----
    {
      f4v acc[4][2];
      gemm_core(sm, t, xhb, xlb, cpk, cn, acc);
#pragma unroll
      for (int i = 0; i < 4; ++i) {
#pragma unroll
        for (int r = 0; r < 4; ++r) {
          int prow = wr * 64 + i * 16 + g * 4 + r;
          float bd = 1e30f; int bk = 0;
#pragma unroll
          for (int j = 0; j < 2; ++j) {
            int col = wc * 32 + j * 16 + lr;
            float s = sm.cns[col] - 2.f * acc[i][j][r];
            if (s < bd || (s == bd && col < bk)) { bd = s; bk = col; }
          }
#pragma unroll
          for (int msk = 1; msk < 16; msk <<= 1) {
            float od = __shfl_xor(bd, msk, 64);
            int   ok = __shfl_xor(bk, msk, 64);
            if (od < bd || (od == bd && ok < bk)) { bd = od; bk = ok; }
          }
          if (lr == 0) { sm.redd[prow * 4 + wc] = bd; sm.redk[prow * 4 + wc] = bk; }
        }
      }
      __syncthreads();
      if (t < NK) {
        float bd = sm.redd[t * 4]; int bk = sm.redk[t * 4];
#pragma unroll
        for (int q = 1; q < 4; ++q) {
          float dq = sm.redd[t * 4 + q]; int kq = sm.redk[t * 4 + q];
          if (dq < bd || (dq == bd && kq < bk)) { bd = dq; bk = kq; }
        }
        cstorei(&ids[pbase + t], bk);
      }
    }
    gbar(flags, gen); ++gen;

    // ---- phase B: D-split segment-sum (32 pgroups x 8 dgroups) ----
    {
      const int pg = b & 31, dg = b >> 5;
      for (int i = t; i < NK * PAD; i += NTHR) accB[i] = 0.f;
      if (t < NK) cntB[t] = 0;
      idslB[t]        = cloadi(&ids[pg * 1024 + t]);
      idslB[NTHR + t] = cloadi(&ids[pg * 1024 + NTHR + t]);
      __syncthreads();
      if (dg == 0) {
        atomicAdd(&cntB[idslB[t]], 1);
        atomicAdd(&cntB[idslB[NTHR + t]], 1);
      }
      const int qd = t & 7, ps = t >> 3;
      const float* xs = x + (size_t)pg * 1024 * DIM + dg * 32 + qd * 4;
#pragma unroll
      for (int s = 0; s < 16; ++s) {
        int pl = s * 64 + ps;
        int id = idslB[pl];
        float4 v = *(const float4*)(xs + (size_t)pl * DIM);
        atomicAdd(&accB[id * PAD + qd * 4 + 0], v.x);
        atomicAdd(&accB[id * PAD + qd * 4 + 1], v.y);
        atomicAdd(&accB[id * PAD + qd * 4 + 2], v.z);
        atomicAdd(&accB[id * PAD + qd * 4 + 3], v.w);
      }
      __syncthreads();
      const int kl = t >> 5, dl = t & 31;
#pragma unroll
      for (int s2 = 0; s2 < 8; ++s2) {
        int k2 = s2 * 16 + kl;
        cstore(&psum[(((size_t)dg * NK + k2) * 32 + pg) * 32 + dl], accB[k2 * PAD + dl]);
      }
      if (dg == 0 && t < NK)
        cstore(&pcnt[(size_t)pg * NK + t], (float)cntB[t]);
    }
    gbar(flags, gen); ++gen;

    // ---- phase C: reduce partials -> means -> packed image + cn (128 blocks) ----
    if (b < NK) {
      const int k = b;
      const int tt = t & 255, hf = t >> 8;
      const int dgc = tt >> 5, dlc = tt & 31;
      float s = 0.f;
#pragma unroll
      for (int p2 = hf * 16; p2 < hf * 16 + 16; ++p2)
        s += cload(&psum[(((size_t)dgc * NK + k) * 32 + p2) * 32 + dlc]);
      redsm[t] = s;
      float cv = 0.f;
      if (t < 32) cv = cload(&pcnt[(size_t)t * NK + k]);
      if (t < 64) {
#pragma unroll
        for (int m = 1; m < 32; m <<= 1) cv += __shfl_xor(cv, m, 64);
      }
      if (t == 0) cntsh = cv;
      __syncthreads();
      float eff = 0.f;
      if (t < DIM) {
        float mean = (redsm[t] + redsm[t + 256]) / cntsh;   // NaN if empty, as ref
        unsigned short hh = f2bf(mean);
        unsigned short ll = f2bf(mean - bf2f(hh));
        hsm[t] = hh; lsm[t] = ll;
        eff = bf2f(hh) + bf2f(ll);
      }
      __syncthreads();                    // all redsm reads + hsm/lsm writes done
      redsm[t] = eff * eff;
      if (t < NK) {
        ull_t wv = (ull_t)hsm[2 * t] | ((ull_t)lsm[2 * t] << 16)
                 | ((ull_t)hsm[2 * t + 1] << 32) | ((ull_t)lsm[2 * t + 1] << 48);
        cstore64(&cpk[(size_t)k * 128 + t], wv);
      }
      __syncthreads();
      for (int st = 256; st > 0; st >>= 1) { if (t < st) redsm[t] += redsm[t + st]; __syncthreads(); }
      if (t == 0) cstore(&cn[k], redsm[0]);
    }
    gbar_pf(flags, gen, xhb, xlb, sm.bufs, t); ++gen;
  }

  // ---------------- final: loss (log-softmax + CE), deterministic reduce ----------------
  {
    f4v acc[4][2];
    gemm_core(sm, t, xhb, xlb, cpk, cn, acc);
#pragma unroll
    for (int i = 0; i < 4; ++i) {
#pragma unroll
      for (int r = 0; r < 4; ++r) {
        int prow = wr * 64 + i * 16 + g * 4 + r;
        float m = -1e30f;
#pragma unroll
        for (int j = 0; j < 2; ++j) m = fmaxf(m, acc[i][j][r]);
#pragma unroll
        for (int msk = 1; msk < 16; msk <<= 1) m = fmaxf(m, __shfl_xor(m, msk, 64));
        if (lr == 0) sm.redd[prow * 4 + wc] = m;
      }
    }
    __syncthreads();
    if (t < NK) {
      float m = sm.redd[t * 4];
#pragma unroll
      for (int q = 1; q < 4; ++q) m = fmaxf(m, sm.redd[t * 4 + q]);
      sm.gmaxs[t] = m;
      sm.labis[t] = cloadi(&ids[pbase + t]);
    }
    __syncthreads();
#pragma unroll
    for (int i = 0; i < 4; ++i) {
#pragma unroll
      for (int r = 0; r < 4; ++r) {
        int prow = wr * 64 + i * 16 + g * 4 + r;
        float m = sm.gmaxs[prow];
        int lab = sm.labis[prow];
        float s = 0.f;
#pragma unroll
        for (int j = 0; j < 2; ++j) {
          int col = wc * 32 + j * 16 + lr;
          float v = acc[i][j][r];
          s += expf(v - m);
          if (col == lab) sm.labvs[prow] = v;
        }
#pragma unroll
        for (int msk = 1; msk < 16; msk <<= 1) s += __shfl_xor(s, msk, 64);
        if (lr == 0) sm.redd[prow * 4 + wc] = s;
      }
    }
    __syncthreads();
    if (t < NK) {
      float se = sm.redd[t * 4] + sm.redd[t * 4 + 1] + sm.redd[t * 4 + 2] + sm.redd[t * 4 + 3];
      float lse = sm.gmaxs[t] + logf(se);
      sm.gmaxs[t] = lse - sm.labvs[t];
    }
    __syncthreads();
    if (t == 0) {
      float tot = 0.f;
      for (int q = 0; q < NK; ++q) tot += sm.gmaxs[q];
      cstore(&outp[b], tot);
    }
  }
  gbar(flags, gen); ++gen;
  if (b == 0) {
    redsm[t] = (t < NBLK) ? cload(&outp[t]) : 0.f;
    __syncthreads();
    for (int s = 256; s > 0; s >>= 1) { if (t < s) redsm[t] += redsm[t + s]; __syncthreads(); }
    if (t == 0) out[0] = redsm[0] * (1.0f / (float)NPTS);
  }
}

extern "C" void kernel_launch(void* const* d_in, const int* in_sizes, int n_in,
                              void* d_out, int out_size, void* d_ws, size_t ws_size,
                              hipStream_t stream) {
  const float* x        = (const float*)d_in[0];
  const int*   init_idx = (const int*)d_in[1];
  float* out = (float*)d_out;
  char* ws = (char*)d_ws;

  // ws layout (bytes):
  ushort_t* xh  = (ushort_t*)(ws);                    // 16777216
  ushort_t* xl  = (ushort_t*)(ws + 16777216);         // 16777216
  ull_t* cpk  = (ull_t*)(ws + 33554432);              // 128*128*8 = 131072
  float* cn   = (float*)(ws + 33685504);              // 512
  int*   ids  = (int*)(ws + 33686016);                // 131072
  float* psum = (float*)(ws + 33817088);              // 8*128*32*32*4 = 4194304
  float* pcnt = (float*)(ws + 38011392);              // 32*128*4 = 16384
  float* outp = (float*)(ws + 38027776);              // 1024
  unsigned* flags = (unsigned*)(ws + 38028800);       // 256*64B = 16384

  // reset barrier state every launch (graph replays include this node)
  hipMemsetAsync(flags, 0, 16384, stream);
  kmeans_fused<<<dim3(NBLK), dim3(NTHR), 0, stream>>>(
      x, init_idx, xh, xl, cpk, cn, ids, psum, pcnt, outp, flags, out);
}